// Round 2
// baseline (329.096 us; speedup 1.0000x reference)
//
#include <hip/hip_runtime.h>

typedef _Float16 f16;
typedef _Float16 f16x4 __attribute__((ext_vector_type(4)));
typedef _Float16 f16x8 __attribute__((ext_vector_type(8)));
typedef float    fx4   __attribute__((ext_vector_type(4)));

#define MODE_PROJ   0
#define MODE_SCORES 1
#define MODE_PV     2

constexpr int Bsz = 4;
constexpr int S   = 2048;
constexpr int DK  = 1024;
constexpr int BM = 128, BN = 256, BK = 64;
constexpr long SD   = (long)S * DK;          // 2M elems
constexpr long SS   = (long)S * S;           // 4M elems
constexpr long BIGN = (long)Bsz * S * DK;    // 8M elems

// async global->LDS, 16B per lane; LDS dest wave-uniform (HW adds lane*16)
__device__ __forceinline__ void glds16(const f16* g, f16* l) {
    __builtin_amdgcn_global_load_lds(
        (const __attribute__((address_space(1))) void*)g,
        (__attribute__((address_space(3))) void*)l, 16, 0, 0);
}

// In-place fp32 -> fp16 conversion, pair-packed:
//   f16 idx = (r>>1)*4096 + (r&1)*1024 + c   (region stride 4096 f16 = 8192 B)
__global__ __launch_bounds__(256)
void convert_kernel(const float* q, const float* k, const float* v,
                    const float* wq, const float* wk, const float* wv)
{
    int bx = blockIdx.x;
    const float* src;
    int blk;
    if (bx < 12288) {
        int t = bx >> 12; blk = bx & 4095;
        src = (t == 0) ? q : (t == 1) ? k : v;
    } else {
        int u = bx - 12288;
        int t = u >> 9; blk = u & 511;
        src = (t == 0) ? wq : (t == 1) ? wk : wv;
    }
    size_t off = (size_t)blk * 2048 + (size_t)threadIdx.x * 8;
    float4 f0 = *(const float4*)(src + off);
    float4 f1 = *(const float4*)(src + off + 4);
    __syncthreads();
    f16x8 h = {(f16)f0.x, (f16)f0.y, (f16)f0.z, (f16)f0.w,
               (f16)f1.x, (f16)f1.y, (f16)f1.z, (f16)f1.w};
    *(f16x8*)((char*)src + (size_t)blk * 8192 + (size_t)threadIdx.x * 16) = h;
}

__device__ __forceinline__ size_t pp(int r, int c) {
    return ((size_t)(r >> 1) << 12) + ((r & 1) << 10) + c;
}

// NT GEMM, fp16. 128x256x64 tiles, 512 threads (8 waves, 2x4), TRIPLE-buffered
// LDS (48 KB/tile x3 = 144 KB), 4-phase schedule per K-tile with COUNTED vmcnt:
// during tile t (compute buf t%3) we stage tile t+2 into buf (t+2)%3 (held
// t-1, fully consumed -> race-free by construction). Tile boundary waits
// s_waitcnt vmcnt(6): the 6 outstanding loads are t+2's; t+1's 6 are older in
// the FIFO and therefore landed. Loads stay in flight across barriers (T4);
// vmcnt(0) only in the 2-iteration tail.
template<int MODE>
__global__ __launch_bounds__(512, 2)
void gemm_kernel(const f16* A0, const f16* A1, const f16* A2,
                 const f16* B0, const f16* B1, const f16* B2,
                 void* O0, void* O1, float* rowsum,
                 int lda, int ldb, int K, int ldo)
{
    __shared__ __attribute__((aligned(16))) f16 lA[3][BM * BK];   // 48 KB
    __shared__ __attribute__((aligned(16))) f16 lB[3][BN * BK];   // 96 KB

    const int tid = threadIdx.x;
    const int id  = blockIdx.x;
    const int z   = blockIdx.y;
    int row0, col0;
    if constexpr (MODE == MODE_PROJ) { row0 = (id & 63) * BM; col0 = (id >> 6) * BN; }
    else                             { row0 = (id & 15) * BM; col0 = (id >> 4) * BN; }

    const int lane = tid & 63;
    const int quad = lane >> 4;
    const int cn   = lane & 15;
    const int w    = tid >> 6;   // 0..7
    const int wm   = w >> 2;     // 0..1  (64 rows each)
    const int wn   = w & 3;      // 0..3  (64 cols each)

    const f16 *Ap, *Bp;
    if constexpr (MODE == MODE_PROJ) {
        Ap = (z == 0) ? A0 : (z == 1) ? A1 : A2;
        Bp = (z == 0) ? B0 : (z == 1) ? B1 : B2;
    } else if constexpr (MODE == MODE_SCORES) {
        Ap = A0 + (long)z * SD;  Bp = B0 + (long)z * SD;
        rowsum += (long)z * S;
    } else {
        Ap = A0 + (long)z * SS;  Bp = B0 + (long)z * SD;
        rowsum += (long)z * S;
    }

    fx4 acc[4][4];
    #pragma unroll
    for (int mt = 0; mt < 4; ++mt)
        #pragma unroll
        for (int nt = 0; nt < 4; ++nt)
            acc[mt][nt] = (fx4){0.f, 0.f, 0.f, 0.f};

    // staging lane map: 8 rows x 8 chunks of 16B; fetch XOR-permuted chunk so
    // LDS physical chunk (lane&7) holds global chunk (lane&7)^(row&7)
    const int lr8 = lane >> 3;            // 0..7 row within 8-row group
    const int swc = (lane & 7) ^ lr8;     // swizzled global chunk
    const int lcS = swc << 3;             // f16 col within BK

    f16x8 af[4];   // current A half: [m(2)][kh(2)]
    f16x8 bf[8];   // full B tile:   [nt(4)][kh(2)]

// A tile: 2 glds per thread
#define STAGE_A(BUF, K0) do {                                                        \
    _Pragma("unroll")                                                                \
    for (int i_ = 0; i_ < 2; ++i_) {                                                 \
        int rb_ = w * 16 + i_ * 8;                                                   \
        if constexpr (MODE == MODE_PROJ)                                             \
            glds16(Ap + pp(row0 + rb_ + lr8, (K0) + lcS), &lA[BUF][rb_ * BK]);       \
        else                                                                         \
            glds16(Ap + (size_t)(row0 + rb_ + lr8) * lda + (K0) + lcS,               \
                   &lA[BUF][rb_ * BK]);                                              \
    }                                                                                \
} while (0)

// B tile halves: 2 glds per thread each
#define STAGE_B(BUF, K0, H) do {                                                     \
    _Pragma("unroll")                                                                \
    for (int i_ = 0; i_ < 2; ++i_) {                                                 \
        int rb_ = w * 32 + ((H) * 2 + i_) * 8;                                       \
        if constexpr (MODE == MODE_PROJ)                                             \
            glds16(Bp + pp(col0 + rb_ + lr8, (K0) + lcS), &lB[BUF][rb_ * BK]);       \
        else                                                                         \
            glds16(Bp + (size_t)(col0 + rb_ + lr8) * ldb + (K0) + lcS,               \
                   &lB[BUF][rb_ * BK]);                                              \
    }                                                                                \
} while (0)

#define LDA_FRAGS(BUF, MH) do {                                                      \
    _Pragma("unroll")                                                                \
    for (int m_ = 0; m_ < 2; ++m_)                                                   \
        _Pragma("unroll")                                                            \
        for (int kk_ = 0; kk_ < 2; ++kk_) {                                          \
            int r_  = wm * 64 + ((MH) * 2 + m_) * 16 + cn;                           \
            int ch_ = ((kk_ << 2) | quad) ^ (r_ & 7);                                \
            af[m_ * 2 + kk_] = *(const f16x8*)&lA[BUF][r_ * BK + ch_ * 8];           \
        }                                                                            \
} while (0)

#define LDB_FRAGS(BUF, NH) do {                                                      \
    _Pragma("unroll")                                                                \
    for (int n_ = 0; n_ < 2; ++n_)                                                   \
        _Pragma("unroll")                                                            \
        for (int kk_ = 0; kk_ < 2; ++kk_) {                                          \
            int nt_ = (NH) * 2 + n_;                                                 \
            int r_  = wn * 64 + nt_ * 16 + cn;                                       \
            int ch_ = ((kk_ << 2) | quad) ^ (r_ & 7);                                \
            bf[nt_ * 2 + kk_] = *(const f16x8*)&lB[BUF][r_ * BK + ch_ * 8];          \
        }                                                                            \
} while (0)

#define QUAD_MFMA(MH, NH) do {                                                       \
    __builtin_amdgcn_s_setprio(1);                                                   \
    _Pragma("unroll")                                                                \
    for (int m_ = 0; m_ < 2; ++m_)                                                   \
        _Pragma("unroll")                                                            \
        for (int n_ = 0; n_ < 2; ++n_) {                                             \
            _Pragma("unroll")                                                        \
            for (int kk_ = 0; kk_ < 2; ++kk_)                                        \
                acc[(MH) * 2 + m_][(NH) * 2 + n_] =                                  \
                    __builtin_amdgcn_mfma_f32_16x16x32_f16(                          \
                        af[m_ * 2 + kk_], bf[((NH) * 2 + n_) * 2 + kk_],             \
                        acc[(MH) * 2 + m_][(NH) * 2 + n_], 0, 0, 0);                 \
        }                                                                            \
    __builtin_amdgcn_s_setprio(0);                                                   \
} while (0)

    const int ntile = K / BK;
    // prologue: stage tiles 0 and 1 (12 loads); wait until only tile1's 6
    // remain outstanding -> tile0 landed.
    STAGE_A(0, 0);  STAGE_B(0, 0, 0);  STAGE_B(0, 0, 1);
    STAGE_A(1, BK); STAGE_B(1, BK, 0); STAGE_B(1, BK, 1);
    asm volatile("s_waitcnt vmcnt(6)" ::: "memory");
    __builtin_amdgcn_s_barrier();

    int cb = 0;
    for (int t = 0; t < ntile; ++t) {
        int sb = cb + 2; if (sb >= 3) sb -= 3;   // stage buffer = (t+2)%3
        const bool pf = (t + 2 < ntile);
        const int kpf = (t + 2) * BK;
        // ---- phase 0: quadrant (0,0); stage t+2 A
        LDA_FRAGS(cb, 0);
        LDB_FRAGS(cb, 0);
        if (pf) STAGE_A(sb, kpf);
        __builtin_amdgcn_s_barrier();
        QUAD_MFMA(0, 0);
        __builtin_amdgcn_s_barrier();
        // ---- phase 1: quadrant (0,1); stage t+2 B half0
        LDB_FRAGS(cb, 1);
        if (pf) STAGE_B(sb, kpf, 0);
        __builtin_amdgcn_s_barrier();
        QUAD_MFMA(0, 1);
        __builtin_amdgcn_s_barrier();
        // ---- phase 2: quadrant (1,1); stage t+2 B half1
        LDA_FRAGS(cb, 1);
        if (pf) STAGE_B(sb, kpf, 1);
        __builtin_amdgcn_s_barrier();
        QUAD_MFMA(1, 1);
        __builtin_amdgcn_s_barrier();
        // ---- phase 3: quadrant (1,0) — frags resident; counted boundary
        QUAD_MFMA(1, 0);
        if (t + 1 < ntile) {
            if (pf) asm volatile("s_waitcnt vmcnt(6)" ::: "memory");
            else    asm volatile("s_waitcnt vmcnt(0)" ::: "memory");
            __builtin_amdgcn_s_barrier();
        }
        cb = cb + 1; if (cb >= 3) cb -= 3;
    }

#undef STAGE_A
#undef STAGE_B
#undef LDA_FRAGS
#undef LDB_FRAGS
#undef QUAD_MFMA

    // C/D layout: col = lane&15, row = quad*4 + reg
    if constexpr (MODE == MODE_PROJ) {
        if (z < 2) {
            f16* O = (f16*)O0 + (long)z * BIGN;   // qp / kp
            #pragma unroll
            for (int mt = 0; mt < 4; ++mt) {
                int r0 = row0 + wm * 64 + mt * 16 + quad * 4;
                #pragma unroll
                for (int nt = 0; nt < 4; ++nt) {
                    int c = col0 + wn * 64 + nt * 16 + cn;
                    #pragma unroll
                    for (int reg = 0; reg < 4; ++reg)
                        O[(size_t)(r0 + reg) * DK + c] = (f16)acc[mt][nt][reg];
                }
            }
        } else {
            // v: transposed store -> vpT[b][e][s]
            #pragma unroll
            for (int mt = 0; mt < 4; ++mt) {
                int r0 = row0 + wm * 64 + mt * 16 + quad * 4;
                int b  = r0 >> 11;
                int s  = r0 & 2047;
                f16* O = (f16*)O1 + (long)b * SD;
                #pragma unroll
                for (int nt = 0; nt < 4; ++nt) {
                    int c = col0 + wn * 64 + nt * 16 + cn;
                    f16x4 h = {(f16)acc[mt][nt][0], (f16)acc[mt][nt][1],
                               (f16)acc[mt][nt][2], (f16)acc[mt][nt][3]};
                    *(f16x4*)&O[(size_t)c * S + s] = h;
                }
            }
        }
    } else if constexpr (MODE == MODE_SCORES) {
        f16* O = (f16*)O0 + (long)z * SS;
        const float sl2e = 0.03125f * 1.44269504f;  // (1/32)*log2(e)
        float rs[4][4];
        #pragma unroll
        for (int mt = 0; mt < 4; ++mt)
            #pragma unroll
            for (int reg = 0; reg < 4; ++reg) rs[mt][reg] = 0.f;
        #pragma unroll
        for (int mt = 0; mt < 4; ++mt) {
            int r0 = row0 + wm * 64 + mt * 16 + quad * 4;
            #pragma unroll
            for (int nt = 0; nt < 4; ++nt) {
                int c = col0 + wn * 64 + nt * 16 + cn;
                #pragma unroll
                for (int reg = 0; reg < 4; ++reg) {
                    float vv = exp2f(acc[mt][nt][reg] * sl2e);
                    rs[mt][reg] += vv;
                    O[(size_t)(r0 + reg) * ldo + c] = (f16)vv;
                }
            }
        }
        #pragma unroll
        for (int mt = 0; mt < 4; ++mt) {
            int r0 = row0 + wm * 64 + mt * 16 + quad * 4;
            #pragma unroll
            for (int reg = 0; reg < 4; ++reg) {
                float vv = rs[mt][reg];
                vv += __shfl_xor(vv, 1);
                vv += __shfl_xor(vv, 2);
                vv += __shfl_xor(vv, 4);
                vv += __shfl_xor(vv, 8);
                if (cn == 0) atomicAdd(&rowsum[r0 + reg], vv);
            }
        }
    } else {  // MODE_PV
        float* O = (float*)O0 + (long)z * SD;
        #pragma unroll
        for (int mt = 0; mt < 4; ++mt) {
            int r0 = row0 + wm * 64 + mt * 16 + quad * 4;
            fx4 rsv = *(const fx4*)&rowsum[r0];
            fx4 inv = {1.f / rsv[0], 1.f / rsv[1], 1.f / rsv[2], 1.f / rsv[3]};
            #pragma unroll
            for (int nt = 0; nt < 4; ++nt) {
                int c = col0 + wn * 64 + nt * 16 + cn;
                #pragma unroll
                for (int reg = 0; reg < 4; ++reg)
                    O[(size_t)(r0 + reg) * ldo + c] = acc[mt][nt][reg] * inv[reg];
            }
        }
    }
}

extern "C" void kernel_launch(void* const* d_in, const int* in_sizes, int n_in,
                              void* d_out, int out_size, void* d_ws, size_t ws_size,
                              hipStream_t stream) {
    const float* q  = (const float*)d_in[0];
    const float* k  = (const float*)d_in[1];
    const float* v  = (const float*)d_in[2];
    const float* wq = (const float*)d_in[3];
    const float* wk = (const float*)d_in[4];
    const float* wv = (const float*)d_in[5];
    float* out = (float*)d_out;

    char* ws = (char*)d_ws;
    f16*   qp     = (f16*)(ws);                          // 16 MB [8192, 1024]
    f16*   kp     = (f16*)(ws + ((size_t)16 << 20));     // 16 MB [8192, 1024]
    f16*   vpT    = (f16*)(ws + ((size_t)32 << 20));     // 16 MB [B][DK][S]
    f16*   E      = (f16*)(ws + ((size_t)48 << 20));     // 32 MB [B][S][S]
    float* rowsum = (float*)(ws + ((size_t)80 << 20));   // 32 KB [B][S]

    hipMemsetAsync(rowsum, 0, (size_t)Bsz * S * sizeof(float), stream);

    convert_kernel<<<13824, 256, 0, stream>>>(q, k, v, wq, wk, wv);

    const f16* qh  = (const f16*)q;
    const f16* kh  = (const f16*)k;
    const f16* vh  = (const f16*)v;
    const f16* wqh = (const f16*)wq;
    const f16* wkh = (const f16*)wk;
    const f16* wvh = (const f16*)wv;

    dim3 blk(512);
    // fused projections: y=0 -> qp, y=1 -> kp, y=2 -> vpT (transposed)
    // 64x4 tiles -> 256 blocks/z, 768 total = 3 exact CU rounds
    gemm_kernel<MODE_PROJ><<<dim3(256, 3), blk, 0, stream>>>(
        qh, kh, vh, wqh, wkh, wvh, qp, vpT, nullptr, DK, DK, DK, DK);
    // scores: E = exp(qp.kp/32), rowsum accumulated; 16x8 tiles x4 = 512 blocks
    gemm_kernel<MODE_SCORES><<<dim3(128, 4), blk, 0, stream>>>(
        qp, nullptr, nullptr, kp, nullptr, nullptr, E, nullptr, rowsum,
        DK, DK, DK, S);
    // PV: out = (E @ vpT^T) / rowsum; 16x4 tiles x4 = 256 blocks
    gemm_kernel<MODE_PV><<<dim3(64, 4), blk, 0, stream>>>(
        E, nullptr, nullptr, vpT, nullptr, nullptr, out, nullptr, rowsum,
        S, S, S, DK);
}

// Round 3
// 303.880 us; speedup vs baseline: 1.0830x; 1.0830x over previous
//
#include <hip/hip_runtime.h>

typedef _Float16 f16;
typedef _Float16 f16x4 __attribute__((ext_vector_type(4)));
typedef _Float16 f16x8 __attribute__((ext_vector_type(8)));
typedef float    fx4   __attribute__((ext_vector_type(4)));

#define MODE_PROJ   0
#define MODE_SCORES 1
#define MODE_PV     2

constexpr int Bsz = 4;
constexpr int S   = 2048;
constexpr int DK  = 1024;
constexpr int BM = 128, BN = 128, BK = 64;   // legacy 128x128 kernel (PV)
constexpr long SD   = (long)S * DK;          // 2M elems
constexpr long SS   = (long)S * S;           // 4M elems
constexpr long BIGN = (long)Bsz * S * DK;    // 8M elems

// async global->LDS, 16B per lane; LDS dest wave-uniform (HW adds lane*16)
__device__ __forceinline__ void glds16(const f16* g, f16* l) {
    __builtin_amdgcn_global_load_lds(
        (const __attribute__((address_space(1))) void*)g,
        (__attribute__((address_space(3))) void*)l, 16, 0, 0);
}

// In-place fp32 -> fp16 conversion, pair-packed:
//   f16 idx = (r>>1)*4096 + (r&1)*1024 + c   (region stride 4096 f16 = 8192 B)
__global__ __launch_bounds__(256)
void convert_kernel(const float* q, const float* k, const float* v,
                    const float* wq, const float* wk, const float* wv)
{
    int bx = blockIdx.x;
    const float* src;
    int blk;
    if (bx < 12288) {
        int t = bx >> 12; blk = bx & 4095;
        src = (t == 0) ? q : (t == 1) ? k : v;
    } else {
        int u = bx - 12288;
        int t = u >> 9; blk = u & 511;
        src = (t == 0) ? wq : (t == 1) ? wk : wv;
    }
    size_t off = (size_t)blk * 2048 + (size_t)threadIdx.x * 8;
    float4 f0 = *(const float4*)(src + off);
    float4 f1 = *(const float4*)(src + off + 4);
    __syncthreads();
    f16x8 h = {(f16)f0.x, (f16)f0.y, (f16)f0.z, (f16)f0.w,
               (f16)f1.x, (f16)f1.y, (f16)f1.z, (f16)f1.w};
    *(f16x8*)((char*)src + (size_t)blk * 8192 + (size_t)threadIdx.x * 16) = h;
}

__device__ __forceinline__ size_t pp(int r, int c) {
    return ((size_t)(r >> 1) << 12) + ((r & 1) << 10) + c;
}

// ---------------------------------------------------------------------------
// 256x256x64 8-wave 4-phase kernel (m201-style). Wave tile 128x64 (2M x 4N).
// Per phase: {ds_read frag subtile || stage phase-matched region} barrier
// {16 MFMA, setprio} vmcnt(6) barrier. Staging: t.ph0->B0(t+1), ph1->B1(t+1),
// ph2->A1(t+1), ph3->A0(t+2) (into buf(t), whose A0 region is dead after ph0).
// Every staged region has >=4 phases of lead; vmcnt(6) (3 phase-stages in
// flight) forces the 4-phase-old stage landed. Never vmcnt(0) except tail.
// Regions (tile rows): A0 = [0,64)u[128,192)   read ph0 (mh=0)
//                      A1 = [64,128)u[192,256) read ph2 (mh=1)
//                      B0 = rows r with (r&63)<32  read ph0 (nh=0)
//                      B1 = rows r with (r&63)>=32 read ph1 (nh=1)
// ---------------------------------------------------------------------------

#define VW6 asm volatile("s_waitcnt vmcnt(6)" ::: "memory")
#define VW4 asm volatile("s_waitcnt vmcnt(4)" ::: "memory")
#define VW2 asm volatile("s_waitcnt vmcnt(2)" ::: "memory")
#define VW0 asm volatile("s_waitcnt vmcnt(0)" ::: "memory")
#define VWX do {} while (0)

template<int MODE>
__global__ __launch_bounds__(512, 2)
void gemm8p_kernel(const f16* A0_, const f16* A1_, const f16* A2_,
                   const f16* B0_, const f16* B1_, const f16* B2_,
                   void* O0, void* O1, float* rowsum,
                   int lda, int ldb, int K, int ldo)
{
    __shared__ __attribute__((aligned(16))) f16 lA[2][2][128 * 64];  // 64 KB
    __shared__ __attribute__((aligned(16))) f16 lB[2][2][128 * 64];  // 64 KB

    const int tid = threadIdx.x;
    const int id  = blockIdx.x;
    const int z   = blockIdx.y;
    int row0, col0;
    if constexpr (MODE == MODE_PROJ) { row0 = (id & 31) * 256; col0 = (id >> 5) * 256; }
    else                             { row0 = (id & 7)  * 256; col0 = (id >> 3) * 256; }

    const int lane = tid & 63;
    const int quad = lane >> 4;
    const int cn   = lane & 15;
    const int w    = tid >> 6;   // 0..7
    const int wm   = w >> 2;     // 0..1: rows wm*128..+127 (== A half wm)
    const int wn   = w & 3;      // 0..3: cols wn*64..+63  (B half = wn>>1)

    const f16 *Ap, *Bp;
    if constexpr (MODE == MODE_PROJ) {
        Ap = (z == 0) ? A0_ : (z == 1) ? A1_ : A2_;
        Bp = (z == 0) ? B0_ : (z == 1) ? B1_ : B2_;
    } else {  // MODE_SCORES
        Ap = A0_ + (long)z * SD;  Bp = B0_ + (long)z * SD;
        rowsum += (long)z * S;
    }

    fx4 acc[8][4];
    #pragma unroll
    for (int am = 0; am < 8; ++am)
        #pragma unroll
        for (int an = 0; an < 4; ++an)
            acc[am][an] = (fx4){0.f, 0.f, 0.f, 0.f};

    // staging lane map: 8 rows x 8 chunks of 16B; fetch XOR-permuted chunk so
    // LDS physical chunk (lane&7) holds global chunk (lane&7)^(row&7)
    const int lr8 = lane >> 3;            // 0..7 row within 8-row group
    const int swc = (lane & 7) ^ lr8;     // swizzled global chunk
    const int lcS = swc << 3;             // f16 col within BK

    f16x8 af[8];   // current A half frags: [mf(4)][kk(2)]
    f16x8 bf0[4];  // B nh=0 frags: [nf(2)][kk(2)]
    f16x8 bf1[4];  // B nh=1 frags

// Each STAGE_* covers 128 rows: logical row L = w*16 + i*8 + lr8, 2 glds/thread.
// Group bases are multiples of 8 and never cross region boundaries, so the
// wave-uniform LDS dest + HW lane*16 scatter lands rows [rb, rb+8) row-major.
#define STAGE_A0(BUF, K0) do {                                               \
    _Pragma("unroll")                                                        \
    for (int i_ = 0; i_ < 2; ++i_) {                                         \
        int Lb_ = w * 16 + i_ * 8;                                           \
        int rb_ = ((Lb_ >> 6) << 7) | (Lb_ & 63);                            \
        f16* d_ = &lA[BUF][rb_ >> 7][(rb_ & 127) * 64];                      \
        int gr_ = row0 + rb_ + lr8;                                          \
        if constexpr (MODE == MODE_PROJ)                                     \
            glds16(Ap + pp(gr_, (K0) + lcS), d_);                            \
        else                                                                 \
            glds16(Ap + (size_t)gr_ * lda + (K0) + lcS, d_);                 \
    }                                                                        \
} while (0)

#define STAGE_A1(BUF, K0) do {                                               \
    _Pragma("unroll")                                                        \
    for (int i_ = 0; i_ < 2; ++i_) {                                         \
        int Lb_ = w * 16 + i_ * 8;                                           \
        int rb_ = (((Lb_ >> 6) << 7) | (Lb_ & 63)) + 64;                     \
        f16* d_ = &lA[BUF][rb_ >> 7][(rb_ & 127) * 64];                      \
        int gr_ = row0 + rb_ + lr8;                                          \
        if constexpr (MODE == MODE_PROJ)                                     \
            glds16(Ap + pp(gr_, (K0) + lcS), d_);                            \
        else                                                                 \
            glds16(Ap + (size_t)gr_ * lda + (K0) + lcS, d_);                 \
    }                                                                        \
} while (0)

#define STAGE_B0(BUF, K0) do {                                               \
    _Pragma("unroll")                                                        \
    for (int i_ = 0; i_ < 2; ++i_) {                                         \
        int Lb_ = w * 16 + i_ * 8;                                           \
        int rb_ = ((Lb_ >> 5) << 6) | (Lb_ & 31);                            \
        f16* d_ = &lB[BUF][rb_ >> 7][(rb_ & 127) * 64];                      \
        int gr_ = col0 + rb_ + lr8;                                          \
        if constexpr (MODE == MODE_PROJ)                                     \
            glds16(Bp + pp(gr_, (K0) + lcS), d_);                            \
        else                                                                 \
            glds16(Bp + (size_t)gr_ * ldb + (K0) + lcS, d_);                 \
    }                                                                        \
} while (0)

#define STAGE_B1(BUF, K0) do {                                               \
    _Pragma("unroll")                                                        \
    for (int i_ = 0; i_ < 2; ++i_) {                                         \
        int Lb_ = w * 16 + i_ * 8;                                           \
        int rb_ = (((Lb_ >> 5) << 6) | (Lb_ & 31)) + 32;                     \
        f16* d_ = &lB[BUF][rb_ >> 7][(rb_ & 127) * 64];                      \
        int gr_ = col0 + rb_ + lr8;                                          \
        if constexpr (MODE == MODE_PROJ)                                     \
            glds16(Bp + pp(gr_, (K0) + lcS), d_);                            \
        else                                                                 \
            glds16(Bp + (size_t)gr_ * ldb + (K0) + lcS, d_);                 \
    }                                                                        \
} while (0)

// Frag reads from own half-tile; rr % 8 == cn % 8 drives the chunk XOR.
#define LDA(BUF, MH) do {                                                    \
    _Pragma("unroll")                                                        \
    for (int mf_ = 0; mf_ < 4; ++mf_)                                        \
        _Pragma("unroll")                                                    \
        for (int kk_ = 0; kk_ < 2; ++kk_) {                                  \
            int rr_ = (MH) * 64 + mf_ * 16 + cn;                             \
            int ch_ = ((kk_ << 2) | quad) ^ (cn & 7);                        \
            af[mf_ * 2 + kk_] = *(const f16x8*)&lA[BUF][wm][rr_ * 64 + ch_ * 8]; \
        }                                                                    \
} while (0)

#define LDB(BUF, NH, BFA) do {                                               \
    _Pragma("unroll")                                                        \
    for (int nf_ = 0; nf_ < 2; ++nf_)                                        \
        _Pragma("unroll")                                                    \
        for (int kk_ = 0; kk_ < 2; ++kk_) {                                  \
            int rr_ = (wn & 1) * 64 + (NH) * 32 + nf_ * 16 + cn;             \
            int ch_ = ((kk_ << 2) | quad) ^ (cn & 7);                        \
            BFA[nf_ * 2 + kk_] = *(const f16x8*)&lB[BUF][wn >> 1][rr_ * 64 + ch_ * 8]; \
        }                                                                    \
} while (0)

#define PH_MFMA(MH, NH, BFA) do {                                            \
    __builtin_amdgcn_s_setprio(1);                                           \
    _Pragma("unroll")                                                        \
    for (int mf_ = 0; mf_ < 4; ++mf_)                                        \
        _Pragma("unroll")                                                    \
        for (int nf_ = 0; nf_ < 2; ++nf_)                                    \
            _Pragma("unroll")                                                \
            for (int kk_ = 0; kk_ < 2; ++kk_)                                \
                acc[(MH) * 4 + mf_][(NH) * 2 + nf_] =                        \
                    __builtin_amdgcn_mfma_f32_16x16x32_f16(                  \
                        af[mf_ * 2 + kk_], BFA[nf_ * 2 + kk_],               \
                        acc[(MH) * 4 + mf_][(NH) * 2 + nf_], 0, 0, 0);       \
    __builtin_amdgcn_s_setprio(0);                                           \
} while (0)

#define TILE(K0, BUF, STG, A0N, W0S, W1S, W2S, W3S) do {                     \
    /* ph0: quadrant (0,0) */                                                \
    LDA(BUF, 0);                                                             \
    LDB(BUF, 0, bf0);                                                        \
    if (STG) STAGE_B0((BUF) ^ 1, (K0) + BK);                                 \
    __builtin_amdgcn_s_barrier();                                            \
    PH_MFMA(0, 0, bf0);                                                      \
    W0S; __builtin_amdgcn_s_barrier();                                       \
    /* ph1: quadrant (0,1) */                                                \
    LDB(BUF, 1, bf1);                                                        \
    if (STG) STAGE_B1((BUF) ^ 1, (K0) + BK);                                 \
    __builtin_amdgcn_s_barrier();                                            \
    PH_MFMA(0, 1, bf1);                                                      \
    W1S; __builtin_amdgcn_s_barrier();                                       \
    /* ph2: quadrant (1,1) */                                                \
    LDA(BUF, 1);                                                             \
    if (STG) STAGE_A1((BUF) ^ 1, (K0) + BK);                                 \
    __builtin_amdgcn_s_barrier();                                            \
    PH_MFMA(1, 1, bf1);                                                      \
    W2S; __builtin_amdgcn_s_barrier();                                       \
    /* ph3: quadrant (1,0) — frags resident, no ds_reads, no mid barrier */  \
    if (A0N) STAGE_A0((BUF), (K0) + 2 * BK);                                 \
    PH_MFMA(1, 0, bf0);                                                      \
    W3S; __builtin_amdgcn_s_barrier();                                       \
} while (0)

    const int ntile = K / BK;   // 16 for both users; even, >= 4
    // prologue: tile0 fully + A0(tile1); wait until A0(0),B0(0) landed.
    STAGE_A0(0, 0); STAGE_B0(0, 0); STAGE_B1(0, 0); STAGE_A1(0, 0);
    STAGE_A0(1, BK);
    VW6; __builtin_amdgcn_s_barrier();

    for (int t = 0; t < ntile - 2; t += 2) {
        TILE(t * BK,       0, 1, 1, VW6, VW6, VW6, VW6);
        TILE((t + 1) * BK, 1, 1, 1, VW6, VW6, VW6, VW6);
    }
    TILE((ntile - 2) * BK, 0, 1, 0, VW6, VW6, VW6, VW4);
    TILE((ntile - 1) * BK, 1, 0, 0, VW2, VW0, VWX, VWX);

#undef STAGE_A0
#undef STAGE_A1
#undef STAGE_B0
#undef STAGE_B1
#undef LDA
#undef LDB
#undef PH_MFMA
#undef TILE

    // C/D layout: col = lane&15, row = quad*4 + reg
    if constexpr (MODE == MODE_PROJ) {
        if (z < 2) {
            f16* O = (f16*)O0 + (long)z * BIGN;   // qp / kp
            #pragma unroll
            for (int am = 0; am < 8; ++am) {
                int r0 = row0 + wm * 128 + am * 16 + quad * 4;
                #pragma unroll
                for (int an = 0; an < 4; ++an) {
                    int c = col0 + wn * 64 + an * 16 + cn;
                    #pragma unroll
                    for (int reg = 0; reg < 4; ++reg)
                        O[(size_t)(r0 + reg) * DK + c] = (f16)acc[am][an][reg];
                }
            }
        } else {
            // v: transposed store -> vpT[b][e][s]
            #pragma unroll
            for (int am = 0; am < 8; ++am) {
                int r0 = row0 + wm * 128 + am * 16 + quad * 4;
                int b  = r0 >> 11;
                int s  = r0 & 2047;
                f16* O = (f16*)O1 + (long)b * SD;
                #pragma unroll
                for (int an = 0; an < 4; ++an) {
                    int c = col0 + wn * 64 + an * 16 + cn;
                    f16x4 h = {(f16)acc[am][an][0], (f16)acc[am][an][1],
                               (f16)acc[am][an][2], (f16)acc[am][an][3]};
                    *(f16x4*)&O[(size_t)c * S + s] = h;
                }
            }
        }
    } else {  // MODE_SCORES
        f16* O = (f16*)O0 + (long)z * SS;
        const float sl2e = 0.03125f * 1.44269504f;  // (1/32)*log2(e)
        #pragma unroll
        for (int am = 0; am < 8; ++am) {
            int r0 = row0 + wm * 128 + am * 16 + quad * 4;
            #pragma unroll
            for (int an = 0; an < 4; ++an) {
                int c = col0 + wn * 64 + an * 16 + cn;
                #pragma unroll
                for (int reg = 0; reg < 4; ++reg) {
                    float vv = exp2f(acc[am][an][reg] * sl2e);
                    acc[am][an][reg] = vv;
                    O[(size_t)(r0 + reg) * ldo + c] = (f16)vv;
                }
            }
        }
        #pragma unroll
        for (int am = 0; am < 8; ++am) {
            int r0 = row0 + wm * 128 + am * 16 + quad * 4;
            #pragma unroll
            for (int reg = 0; reg < 4; ++reg) {
                float vv = acc[am][0][reg] + acc[am][1][reg] +
                           acc[am][2][reg] + acc[am][3][reg];
                vv += __shfl_xor(vv, 1);
                vv += __shfl_xor(vv, 2);
                vv += __shfl_xor(vv, 4);
                vv += __shfl_xor(vv, 8);
                if (cn == 0) atomicAdd(&rowsum[r0 + reg], vv);
            }
        }
    }
}

// ---------------------------------------------------------------------------
// Legacy 128x128x64 kernel (R0, unchanged) — used for PV (512 blocks, 2/CU).
// ---------------------------------------------------------------------------
template<int MODE>
__global__ __launch_bounds__(256, 4)
void gemm_kernel(const f16* A0, const f16* A1, const f16* A2,
                 const f16* B0, const f16* B1, const f16* B2,
                 void* O0, void* O1, float* rowsum,
                 int lda, int ldb, int K, int ldo)
{
    __shared__ f16 lA[BM * BK];   // 16 KB
    __shared__ f16 lB[BN * BK];   // 16 KB

    const int tid = threadIdx.x;
    const int id  = blockIdx.x;
    const int z   = blockIdx.y;
    int row0, col0;
    if constexpr (MODE == MODE_PROJ) { row0 = (id & 63) * BM; col0 = (id >> 6) * BN; }
    else                             { row0 = (id & 15) * BM; col0 = (id >> 4) * BN; }

    const int lane = tid & 63;
    const int quad = lane >> 4;
    const int cn   = lane & 15;
    const int w    = tid >> 6;
    const int wm   = w >> 1;
    const int wn   = w & 1;

    const f16 *Ap, *Bp;
    if constexpr (MODE == MODE_PROJ) {
        Ap = (z == 0) ? A0 : (z == 1) ? A1 : A2;
        Bp = (z == 0) ? B0 : (z == 1) ? B1 : B2;
    } else if constexpr (MODE == MODE_SCORES) {
        Ap = A0 + (long)z * SD;  Bp = B0 + (long)z * SD;
        rowsum += (long)z * S;
    } else {
        Ap = A0 + (long)z * SS;  Bp = B0 + (long)z * SD;
        rowsum += (long)z * S;
    }

    fx4 acc[4][4];
    #pragma unroll
    for (int mt = 0; mt < 4; ++mt)
        #pragma unroll
        for (int nt = 0; nt < 4; ++nt)
            acc[mt][nt] = (fx4){0.f, 0.f, 0.f, 0.f};

    const int lr8 = lane >> 3;
    const int swc = (lane & 7) ^ lr8;
    const int lcS = swc << 3;

    for (int k0 = 0; k0 < K; k0 += BK) {
        __syncthreads();
        #pragma unroll
        for (int i = 0; i < 4; ++i) {
            int rb = w * 32 + i * 8;
            if constexpr (MODE == MODE_PROJ) {
                glds16(Ap + pp(row0 + rb + lr8, k0 + lcS), &lA[rb * BK]);
                glds16(Bp + pp(col0 + rb + lr8, k0 + lcS), &lB[rb * BK]);
            } else {
                glds16(Ap + (size_t)(row0 + rb + lr8) * lda + k0 + lcS, &lA[rb * BK]);
                glds16(Bp + (size_t)(col0 + rb + lr8) * ldb + k0 + lcS, &lB[rb * BK]);
            }
        }
        __syncthreads();

        #pragma unroll
        for (int kh = 0; kh < 2; ++kh) {
            f16x8 af[4], bf[4];
            #pragma unroll
            for (int mt = 0; mt < 4; ++mt) {
                int r = wm * 64 + mt * 16 + cn;
                int ch = ((kh << 2) | quad) ^ (r & 7);
                af[mt] = *(const f16x8*)&lA[r * BK + ch * 8];
            }
            #pragma unroll
            for (int nt = 0; nt < 4; ++nt) {
                int r = wn * 64 + nt * 16 + cn;
                int ch = ((kh << 2) | quad) ^ (r & 7);
                bf[nt] = *(const f16x8*)&lB[r * BK + ch * 8];
            }
            #pragma unroll
            for (int mt = 0; mt < 4; ++mt)
                #pragma unroll
                for (int nt = 0; nt < 4; ++nt)
                    acc[mt][nt] = __builtin_amdgcn_mfma_f32_16x16x32_f16(
                        af[mt], bf[nt], acc[mt][nt], 0, 0, 0);
        }
    }

    if constexpr (MODE == MODE_PROJ) {
        if (z < 2) {
            f16* O = (f16*)O0 + (long)z * BIGN;
            #pragma unroll
            for (int mt = 0; mt < 4; ++mt) {
                int r0 = row0 + wm * 64 + mt * 16 + quad * 4;
                #pragma unroll
                for (int nt = 0; nt < 4; ++nt) {
                    int c = col0 + wn * 64 + nt * 16 + cn;
                    #pragma unroll
                    for (int reg = 0; reg < 4; ++reg)
                        O[(size_t)(r0 + reg) * DK + c] = (f16)acc[mt][nt][reg];
                }
            }
        } else {
            #pragma unroll
            for (int mt = 0; mt < 4; ++mt) {
                int r0 = row0 + wm * 64 + mt * 16 + quad * 4;
                int b  = r0 >> 11;
                int s  = r0 & 2047;
                f16* O = (f16*)O1 + (long)b * SD;
                #pragma unroll
                for (int nt = 0; nt < 4; ++nt) {
                    int c = col0 + wn * 64 + nt * 16 + cn;
                    f16x4 h = {(f16)acc[mt][nt][0], (f16)acc[mt][nt][1],
                               (f16)acc[mt][nt][2], (f16)acc[mt][nt][3]};
                    *(f16x4*)&O[(size_t)c * S + s] = h;
                }
            }
        }
    } else if constexpr (MODE == MODE_SCORES) {
        f16* O = (f16*)O0 + (long)z * SS;
        const float sl2e = 0.03125f * 1.44269504f;
        float rs[4][4];
        #pragma unroll
        for (int mt = 0; mt < 4; ++mt)
            #pragma unroll
            for (int reg = 0; reg < 4; ++reg) rs[mt][reg] = 0.f;
        #pragma unroll
        for (int mt = 0; mt < 4; ++mt) {
            int r0 = row0 + wm * 64 + mt * 16 + quad * 4;
            #pragma unroll
            for (int nt = 0; nt < 4; ++nt) {
                int c = col0 + wn * 64 + nt * 16 + cn;
                #pragma unroll
                for (int reg = 0; reg < 4; ++reg) {
                    float vv = exp2f(acc[mt][nt][reg] * sl2e);
                    rs[mt][reg] += vv;
                    O[(size_t)(r0 + reg) * ldo + c] = (f16)vv;
                }
            }
        }
        #pragma unroll
        for (int mt = 0; mt < 4; ++mt) {
            int r0 = row0 + wm * 64 + mt * 16 + quad * 4;
            #pragma unroll
            for (int reg = 0; reg < 4; ++reg) {
                float vv = rs[mt][reg];
                vv += __shfl_xor(vv, 1);
                vv += __shfl_xor(vv, 2);
                vv += __shfl_xor(vv, 4);
                vv += __shfl_xor(vv, 8);
                if (cn == 0) atomicAdd(&rowsum[r0 + reg], vv);
            }
        }
    } else {  // MODE_PV
        float* O = (float*)O0 + (long)z * SD;
        #pragma unroll
        for (int mt = 0; mt < 4; ++mt) {
            int r0 = row0 + wm * 64 + mt * 16 + quad * 4;
            fx4 rsv = *(const fx4*)&rowsum[r0];
            fx4 inv = {1.f / rsv[0], 1.f / rsv[1], 1.f / rsv[2], 1.f / rsv[3]};
            #pragma unroll
            for (int nt = 0; nt < 4; ++nt) {
                int c = col0 + wn * 64 + nt * 16 + cn;
                #pragma unroll
                for (int reg = 0; reg < 4; ++reg)
                    O[(size_t)(r0 + reg) * ldo + c] = acc[mt][nt][reg] * inv[reg];
            }
        }
    }
}

extern "C" void kernel_launch(void* const* d_in, const int* in_sizes, int n_in,
                              void* d_out, int out_size, void* d_ws, size_t ws_size,
                              hipStream_t stream) {
    const float* q  = (const float*)d_in[0];
    const float* k  = (const float*)d_in[1];
    const float* v  = (const float*)d_in[2];
    const float* wq = (const float*)d_in[3];
    const float* wk = (const float*)d_in[4];
    const float* wv = (const float*)d_in[5];
    float* out = (float*)d_out;

    char* ws = (char*)d_ws;
    f16*   qp     = (f16*)(ws);                          // 16 MB [8192, 1024]
    f16*   kp     = (f16*)(ws + ((size_t)16 << 20));     // 16 MB [8192, 1024]
    f16*   vpT    = (f16*)(ws + ((size_t)32 << 20));     // 16 MB [B][DK][S]
    f16*   E      = (f16*)(ws + ((size_t)48 << 20));     // 32 MB [B][S][S]
    float* rowsum = (float*)(ws + ((size_t)80 << 20));   // 32 KB [B][S]

    hipMemsetAsync(rowsum, 0, (size_t)Bsz * S * sizeof(float), stream);

    convert_kernel<<<13824, 256, 0, stream>>>(q, k, v, wq, wk, wv);

    const f16* qh  = (const f16*)q;
    const f16* kh  = (const f16*)k;
    const f16* vh  = (const f16*)v;
    const f16* wqh = (const f16*)wq;
    const f16* wkh = (const f16*)wk;
    const f16* wvh = (const f16*)wv;

    // fused projections (256x256 8-phase): 32x4 tiles -> 128 blocks/z, 3 z
    gemm8p_kernel<MODE_PROJ><<<dim3(128, 3), 512, 0, stream>>>(
        qh, kh, vh, wqh, wkh, wvh, qp, vpT, nullptr, DK, DK, DK, DK);
    // scores (256x256 8-phase): 8x8 tiles x4 z = 256 blocks = 1 exact round
    gemm8p_kernel<MODE_SCORES><<<dim3(64, 4), 512, 0, stream>>>(
        qp, nullptr, nullptr, kp, nullptr, nullptr, E, nullptr, rowsum,
        DK, DK, DK, S);
    // PV (legacy 128x128): out = (E @ vpT^T) / rowsum; 512 blocks, 2/CU
    gemm_kernel<MODE_PV><<<dim3(128, 4), 256, 0, stream>>>(
        E, nullptr, nullptr, vpT, nullptr, nullptr, out, nullptr, rowsum,
        S, S, S, DK);
}

// Round 4
// 298.119 us; speedup vs baseline: 1.1039x; 1.0193x over previous
//
#include <hip/hip_runtime.h>

typedef _Float16 f16;
typedef _Float16 f16x4 __attribute__((ext_vector_type(4)));
typedef _Float16 f16x8 __attribute__((ext_vector_type(8)));
typedef float    fx4   __attribute__((ext_vector_type(4)));

#define MODE_PROJ   0
#define MODE_SCORES 1
#define MODE_PV     2

constexpr int Bsz = 4;
constexpr int S   = 2048;
constexpr int DK  = 1024;
constexpr int BM = 128, BN = 128, BK = 64;
constexpr long SD   = (long)S * DK;          // 2M elems
constexpr long SS   = (long)S * S;           // 4M elems
constexpr long BIGN = (long)Bsz * S * DK;    // 8M elems

// async global->LDS, 16B per lane; LDS dest wave-uniform (HW adds lane*16)
__device__ __forceinline__ void glds16(const f16* g, f16* l) {
    __builtin_amdgcn_global_load_lds(
        (const __attribute__((address_space(1))) void*)g,
        (__attribute__((address_space(3))) void*)l, 16, 0, 0);
}

// pair-packed f16 layout: f16 idx = (r>>1)<<SH | (r&1)<<10 | c
//   SH=12: gapped (in-place over fp32 buffer, region stride 8192 B)
//   SH=11: dense  (workspace copy, region stride 4096 B)
template<int SH>
__device__ __forceinline__ size_t pp(int r, int c) {
    return ((size_t)(r >> 1) << SH) + ((r & 1) << 10) + c;
}

// fp32 -> f16 pair-packed conversion. 3456 blocks x 4 chunks (grid-strided,
// buffered in regs so one barrier covers the in-place RMW hazard). Blocks
// 0..7 additionally zero rowsum (replaces the separate memset dispatch).
__global__ __launch_bounds__(256)
void convert_kernel(const float* q, const float* k, const float* v,
                    const float* wq, const float* wk, const float* wv,
                    f16* dq, f16* dk, f16* dv,
                    f16* dwq, f16* dwk, f16* dwv,
                    int sh, int inplace, float* rowsum)
{
    const int tid = threadIdx.x;
    if (blockIdx.x < 8) {
        float4 zz = {0.f, 0.f, 0.f, 0.f};
        *(float4*)&rowsum[(blockIdx.x * 256 + tid) * 4] = zz;
    }
    float4 f0[4], f1[4];
    f16* dst[4];
    size_t doff[4];
    #pragma unroll
    for (int i = 0; i < 4; ++i) {
        int cx = blockIdx.x + i * 3456;
        const float* s; f16* d; int blk;
        if (cx < 12288) {
            int t = cx >> 12; blk = cx & 4095;
            s = (t == 0) ? q : (t == 1) ? k : v;
            d = (t == 0) ? dq : (t == 1) ? dk : dv;
        } else {
            int u = cx - 12288;
            int t = u >> 9; blk = u & 511;
            s = (t == 0) ? wq : (t == 1) ? wk : wv;
            d = (t == 0) ? dwq : (t == 1) ? dwk : dwv;
        }
        size_t off = (size_t)blk * 2048 + (size_t)tid * 8;
        f0[i] = *(const float4*)(s + off);
        f1[i] = *(const float4*)(s + off + 4);
        dst[i]  = d;
        doff[i] = ((size_t)blk << (sh + 1)) + (size_t)tid * 16;
    }
    if (inplace) __syncthreads();   // uniform branch; RMW hazard only in-place
    #pragma unroll
    for (int i = 0; i < 4; ++i) {
        f16x8 h = {(f16)f0[i].x, (f16)f0[i].y, (f16)f0[i].z, (f16)f0[i].w,
                   (f16)f1[i].x, (f16)f1[i].y, (f16)f1[i].z, (f16)f1[i].w};
        *(f16x8*)((char*)dst[i] + doff[i]) = h;
    }
}

// NT GEMM, fp16, glds16 staging with XOR bank swizzle, 128x128x64 tiles.
// (R0 structure, proven 296 us total; 8-phase/256^2 restructures all regressed
//  at 1 block/CU -- see rounds 1-3. Do not re-attempt without new evidence.)
template<int MODE, int SH>
__global__ __launch_bounds__(256, 4)
void gemm_kernel(const f16* A0, const f16* A1, const f16* A2,
                 const f16* B0, const f16* B1, const f16* B2,
                 void* O0, void* O1, float* rowsum,
                 int lda, int ldb, int K, int ldo)
{
    __shared__ f16 lA[BM * BK];   // 16 KB
    __shared__ f16 lB[BN * BK];   // 16 KB

    const int tid = threadIdx.x;
    const int id  = blockIdx.x;
    const int z   = blockIdx.y;
    int row0, col0;
    if constexpr (MODE == MODE_PROJ) { row0 = (id & 63) * BM; col0 = (id >> 6) * BN; }
    else                             { row0 = (id & 15) * BM; col0 = (id >> 4) * BN; }

    const int lane = tid & 63;
    const int quad = lane >> 4;
    const int cn   = lane & 15;
    const int w    = tid >> 6;
    const int wm   = w >> 1;
    const int wn   = w & 1;

    const f16 *Ap, *Bp;
    if constexpr (MODE == MODE_PROJ) {
        Ap = (z == 0) ? A0 : (z == 1) ? A1 : A2;
        Bp = (z == 0) ? B0 : (z == 1) ? B1 : B2;
    } else if constexpr (MODE == MODE_SCORES) {
        Ap = A0 + (long)z * SD;  Bp = B0 + (long)z * SD;
        rowsum += (long)z * S;
    } else {
        Ap = A0 + (long)z * SS;  Bp = B0 + (long)z * SD;
        rowsum += (long)z * S;
    }

    fx4 acc[4][4];
    #pragma unroll
    for (int mt = 0; mt < 4; ++mt)
        #pragma unroll
        for (int nt = 0; nt < 4; ++nt)
            acc[mt][nt] = (fx4){0.f, 0.f, 0.f, 0.f};

    // staging lane map: 8 rows x 8 chunks of 16B; fetch XOR-permuted chunk so
    // LDS physical chunk (lane&7) holds global chunk (lane&7)^(row&7)
    const int lr8 = lane >> 3;            // 0..7 row within 8-row group
    const int swc = (lane & 7) ^ lr8;     // swizzled global chunk
    const int lcS = swc << 3;             // f16 col within BK

    for (int k0 = 0; k0 < K; k0 += BK) {
        __syncthreads();
        #pragma unroll
        for (int i = 0; i < 4; ++i) {
            int rb = w * 32 + i * 8;      // wave-uniform row base
            if constexpr (MODE == MODE_PROJ) {
                glds16(Ap + pp<SH>(row0 + rb + lr8, k0 + lcS), &lA[rb * BK]);
                glds16(Bp + pp<SH>(col0 + rb + lr8, k0 + lcS), &lB[rb * BK]);
            } else {
                glds16(Ap + (size_t)(row0 + rb + lr8) * lda + k0 + lcS, &lA[rb * BK]);
                glds16(Bp + (size_t)(col0 + rb + lr8) * ldb + k0 + lcS, &lB[rb * BK]);
            }
        }
        __syncthreads();

        #pragma unroll
        for (int kh = 0; kh < 2; ++kh) {
            f16x8 af[4], bf[4];
            #pragma unroll
            for (int mt = 0; mt < 4; ++mt) {
                int r = wm * 64 + mt * 16 + cn;
                int ch = ((kh << 2) | quad) ^ (r & 7);
                af[mt] = *(const f16x8*)&lA[r * BK + ch * 8];
            }
            #pragma unroll
            for (int nt = 0; nt < 4; ++nt) {
                int r = wn * 64 + nt * 16 + cn;
                int ch = ((kh << 2) | quad) ^ (r & 7);
                bf[nt] = *(const f16x8*)&lB[r * BK + ch * 8];
            }
            #pragma unroll
            for (int mt = 0; mt < 4; ++mt)
                #pragma unroll
                for (int nt = 0; nt < 4; ++nt)
                    acc[mt][nt] = __builtin_amdgcn_mfma_f32_16x16x32_f16(
                        af[mt], bf[nt], acc[mt][nt], 0, 0, 0);
        }
    }

    // C/D layout: col = lane&15, row = quad*4 + reg
    if constexpr (MODE == MODE_PROJ) {
        if (z < 2) {
            f16* O = (f16*)O0 + (long)z * BIGN;   // qp / kp
            #pragma unroll
            for (int mt = 0; mt < 4; ++mt) {
                int r0 = row0 + wm * 64 + mt * 16 + quad * 4;
                #pragma unroll
                for (int nt = 0; nt < 4; ++nt) {
                    int c = col0 + wn * 64 + nt * 16 + cn;
                    #pragma unroll
                    for (int reg = 0; reg < 4; ++reg)
                        O[(size_t)(r0 + reg) * DK + c] = (f16)acc[mt][nt][reg];
                }
            }
        } else {
            // v: transposed store -> vpT[b][e][s]
            #pragma unroll
            for (int mt = 0; mt < 4; ++mt) {
                int r0 = row0 + wm * 64 + mt * 16 + quad * 4;
                int b  = r0 >> 11;
                int s  = r0 & 2047;
                f16* O = (f16*)O1 + (long)b * SD;
                #pragma unroll
                for (int nt = 0; nt < 4; ++nt) {
                    int c = col0 + wn * 64 + nt * 16 + cn;
                    f16x4 h = {(f16)acc[mt][nt][0], (f16)acc[mt][nt][1],
                               (f16)acc[mt][nt][2], (f16)acc[mt][nt][3]};
                    *(f16x4*)&O[(size_t)c * S + s] = h;
                }
            }
        }
    } else if constexpr (MODE == MODE_SCORES) {
        f16* O = (f16*)O0 + (long)z * SS;
        const float sl2e = 0.03125f * 1.44269504f;  // (1/32)*log2(e)
        float rs[4][4];
        #pragma unroll
        for (int mt = 0; mt < 4; ++mt)
            #pragma unroll
            for (int reg = 0; reg < 4; ++reg) rs[mt][reg] = 0.f;
        #pragma unroll
        for (int mt = 0; mt < 4; ++mt) {
            int r0 = row0 + wm * 64 + mt * 16 + quad * 4;
            #pragma unroll
            for (int nt = 0; nt < 4; ++nt) {
                int c = col0 + wn * 64 + nt * 16 + cn;
                #pragma unroll
                for (int reg = 0; reg < 4; ++reg) {
                    float vv = exp2f(acc[mt][nt][reg] * sl2e);
                    rs[mt][reg] += vv;
                    O[(size_t)(r0 + reg) * ldo + c] = (f16)vv;
                }
            }
        }
        #pragma unroll
        for (int mt = 0; mt < 4; ++mt) {
            int r0 = row0 + wm * 64 + mt * 16 + quad * 4;
            #pragma unroll
            for (int reg = 0; reg < 4; ++reg) {
                float vv = rs[mt][reg];
                vv += __shfl_xor(vv, 1);
                vv += __shfl_xor(vv, 2);
                vv += __shfl_xor(vv, 4);
                vv += __shfl_xor(vv, 8);
                if (cn == 0) atomicAdd(&rowsum[r0 + reg], vv);
            }
        }
    } else {  // MODE_PV
        float* O = (float*)O0 + (long)z * SD;
        #pragma unroll
        for (int mt = 0; mt < 4; ++mt) {
            int r0 = row0 + wm * 64 + mt * 16 + quad * 4;
            fx4 rsv = *(const fx4*)&rowsum[r0];
            fx4 inv = {1.f / rsv[0], 1.f / rsv[1], 1.f / rsv[2], 1.f / rsv[3]};
            #pragma unroll
            for (int nt = 0; nt < 4; ++nt) {
                int c = col0 + wn * 64 + nt * 16 + cn;
                #pragma unroll
                for (int reg = 0; reg < 4; ++reg)
                    O[(size_t)(r0 + reg) * ldo + c] = acc[mt][nt][reg] * inv[reg];
            }
        }
    }
}

extern "C" void kernel_launch(void* const* d_in, const int* in_sizes, int n_in,
                              void* d_out, int out_size, void* d_ws, size_t ws_size,
                              hipStream_t stream) {
    const float* q  = (const float*)d_in[0];
    const float* k  = (const float*)d_in[1];
    const float* v  = (const float*)d_in[2];
    const float* wq = (const float*)d_in[3];
    const float* wk = (const float*)d_in[4];
    const float* wv = (const float*)d_in[5];
    float* out = (float*)d_out;

    char* ws = (char*)d_ws;
    f16*   qp     = (f16*)(ws);                          // 16 MB [8192, 1024]
    f16*   kp     = (f16*)(ws + ((size_t)16 << 20));     // 16 MB [8192, 1024]
    f16*   vpT    = (f16*)(ws + ((size_t)32 << 20));     // 16 MB [B][DK][S]
    f16*   E      = (f16*)(ws + ((size_t)48 << 20));     // 32 MB [B][S][S]
    float* rowsum = (float*)(ws + ((size_t)80 << 20));   // 32 KB [B][S]

    // f16 input copies (dense pair-packed) live at 81 MiB when ws permits;
    // otherwise fall back to the proven in-place (gapped) conversion.
    const bool usews = ws_size >= ((size_t)135 << 20);
    char* cb = ws + ((size_t)81 << 20);
    f16 *dq, *dk, *dv, *dwq, *dwk, *dwv;
    if (usews) {
        dq  = (f16*)(cb);
        dk  = (f16*)(cb + ((size_t)16 << 20));
        dv  = (f16*)(cb + ((size_t)32 << 20));
        dwq = (f16*)(cb + ((size_t)48 << 20));
        dwk = (f16*)(cb + ((size_t)50 << 20));
        dwv = (f16*)(cb + ((size_t)52 << 20));
    } else {
        dq  = (f16*)q;  dk  = (f16*)k;  dv  = (f16*)v;
        dwq = (f16*)wq; dwk = (f16*)wk; dwv = (f16*)wv;
    }

    convert_kernel<<<3456, 256, 0, stream>>>(
        q, k, v, wq, wk, wv, dq, dk, dv, dwq, dwk, dwv,
        usews ? 11 : 12, usews ? 0 : 1, rowsum);

    dim3 blk(256);
    // fused projections: y=0 -> qp, y=1 -> kp, y=2 -> vpT (transposed)
    if (usews)
        gemm_kernel<MODE_PROJ, 11><<<dim3(512, 3), blk, 0, stream>>>(
            dq, dk, dv, dwq, dwk, dwv, qp, vpT, nullptr, DK, DK, DK, DK);
    else
        gemm_kernel<MODE_PROJ, 12><<<dim3(512, 3), blk, 0, stream>>>(
            dq, dk, dv, dwq, dwk, dwv, qp, vpT, nullptr, DK, DK, DK, DK);
    // scores: E = exp(qp.kp/32), rowsum accumulated
    gemm_kernel<MODE_SCORES, 12><<<dim3(256, 4), blk, 0, stream>>>(
        qp, nullptr, nullptr, kp, nullptr, nullptr, E, nullptr, rowsum,
        DK, DK, DK, S);
    // PV: out = (E @ vpT^T) / rowsum
    gemm_kernel<MODE_PV, 12><<<dim3(128, 4), blk, 0, stream>>>(
        E, nullptr, nullptr, vpT, nullptr, nullptr, out, nullptr, rowsum,
        S, S, S, DK);
}